// Round 1
// baseline (528.283 us; speedup 1.0000x reference)
//
#include <hip/hip_runtime.h>

// VectorQuantizer: x[32,2048,256] f32, W[1024,256] f32.
// Outputs (concat f32): quantized[16777216], loss[1], idx[65536].

#define ND_TOTAL 16777216   // 32*2048*256
#define NROWS    65536      // 32*2048
#define DDIM     256
#define KCODES   1024
#define BM 128              // rows per block
#define BK 128              // codes per K-tile
#define DC 16               // D chunk staged in LDS

// ws layout: ws[0] = loss accumulator, ws[64..64+1024) = ||W_k||^2

__global__ void vq_prep(const float* __restrict__ W, float* __restrict__ ws) {
    int k = blockIdx.x * blockDim.x + threadIdx.x;
    if (k == 0) ws[0] = 0.0f;   // zero loss accumulator (ws is poisoned each launch)
    if (k < KCODES) {
        const float4* wr = (const float4*)(W + (size_t)k * DDIM);
        float s = 0.0f;
        #pragma unroll 4
        for (int i = 0; i < DDIM / 4; ++i) {
            float4 v = wr[i];
            s = fmaf(v.x, v.x, s);
            s = fmaf(v.y, v.y, s);
            s = fmaf(v.z, v.z, s);
            s = fmaf(v.w, v.w, s);
        }
        ws[64 + k] = s;
    }
}

__global__ __launch_bounds__(256, 2) void vq_main(
    const float* __restrict__ x, const float* __restrict__ W,
    const float* __restrict__ wsq, float* __restrict__ qout,
    float* __restrict__ loss_accum, float* __restrict__ idx_out)
{
    __shared__ float Xs[DC][BM];       // transposed: Xs[d][row]
    __shared__ float Wst[DC][BK];      // transposed: Wst[d][code]
    __shared__ float red_val[BM][16];
    __shared__ int   red_ki[BM][16];
    __shared__ int   final_k[BM];

    const int tid  = threadIdx.x;
    const int trow = tid >> 4;     // 0..15
    const int tcol = tid & 15;     // 0..15
    const int row0 = blockIdx.x * BM;

    float best[8];
    int   bestk[8];
    #pragma unroll
    for (int i = 0; i < 8; ++i) { best[i] = 3.4e38f; bestk[i] = 0; }

    const int rload = tid >> 1;    // 0..127
    const int fg    = tid & 1;

    for (int kt = 0; kt < KCODES; kt += BK) {
        float acc[8][8];
        #pragma unroll
        for (int i = 0; i < 8; ++i)
            #pragma unroll
            for (int j = 0; j < 8; ++j) acc[i][j] = 0.0f;

        for (int dc = 0; dc < DDIM; dc += DC) {
            __syncthreads();   // protect previous chunk's reads before overwrite
            const float* xp = x + (size_t)(row0 + rload) * DDIM + dc;
            const float* wp = W + (size_t)(kt + rload) * DDIM + dc;
            #pragma unroll
            for (int it = 0; it < 2; ++it) {
                int g = fg * 2 + it;           // float4 group within chunk (0..3)
                float4 xv = *(const float4*)(xp + g * 4);
                float4 wv = *(const float4*)(wp + g * 4);
                Xs[g*4+0][rload] = xv.x; Xs[g*4+1][rload] = xv.y;
                Xs[g*4+2][rload] = xv.z; Xs[g*4+3][rload] = xv.w;
                Wst[g*4+0][rload] = wv.x; Wst[g*4+1][rload] = wv.y;
                Wst[g*4+2][rload] = wv.z; Wst[g*4+3][rload] = wv.w;
            }
            __syncthreads();
            #pragma unroll
            for (int d = 0; d < DC; ++d) {
                float a[8], b[8];
                *(float4*)(&a[0]) = *(const float4*)(&Xs[d][trow * 4]);
                *(float4*)(&a[4]) = *(const float4*)(&Xs[d][64 + trow * 4]);
                *(float4*)(&b[0]) = *(const float4*)(&Wst[d][tcol * 4]);
                *(float4*)(&b[4]) = *(const float4*)(&Wst[d][64 + tcol * 4]);
                #pragma unroll
                for (int i = 0; i < 8; ++i)
                    #pragma unroll
                    for (int j = 0; j < 8; ++j)
                        acc[i][j] = fmaf(a[i], b[j], acc[i][j]);
            }
        }

        // fold this K-tile into the running argmin (||x||^2 dropped: per-row const)
        #pragma unroll
        for (int j = 0; j < 8; ++j) {
            int kk = kt + ((j < 4) ? (tcol * 4 + j) : (64 + tcol * 4 + (j - 4)));
            float w2 = wsq[kk];
            #pragma unroll
            for (int i = 0; i < 8; ++i) {
                float d2 = fmaf(-2.0f, acc[i][j], w2);
                if (d2 < best[i]) { best[i] = d2; bestk[i] = kk; }  // k ascending in-thread
            }
        }
    }

    // cross-thread (tcol) argmin reduction per row, np tie-break = lowest k
    __syncthreads();
    #pragma unroll
    for (int i = 0; i < 8; ++i) {
        int r = (i < 4) ? (trow * 4 + i) : (64 + trow * 4 + (i - 4));
        red_val[r][tcol] = best[i];
        red_ki[r][tcol]  = bestk[i];
    }
    __syncthreads();
    if (tid < BM) {
        float bv = red_val[tid][0];
        int   bk = red_ki[tid][0];
        #pragma unroll
        for (int c = 1; c < 16; ++c) {
            float v  = red_val[tid][c];
            int   kk = red_ki[tid][c];
            if (v < bv || (v == bv && kk < bk)) { bv = v; bk = kk; }
        }
        final_k[tid] = bk;
        idx_out[row0 + tid] = (float)bk;   // out dtype is f32; small ints exact
    }
    __syncthreads();

    // epilogue: gather W[idx] -> quantized (coalesced: 64 lanes = 1 row of float4),
    // accumulate sum((w-x)^2) for loss
    const int c4   = tid & 63;   // float4 column 0..63
    const int rsub = tid >> 6;   // 0..3
    float lsum = 0.0f;
    for (int it = 0; it < 32; ++it) {
        int r = it * 4 + rsub;
        int myk = final_k[r];
        float4 wv = *((const float4*)(W + (size_t)myk * DDIM) + c4);
        float4 xv = *((const float4*)(x + (size_t)(row0 + r) * DDIM) + c4);
        *((float4*)(qout + (size_t)(row0 + r) * DDIM) + c4) = wv;
        float dx = wv.x - xv.x, dy = wv.y - xv.y;
        float dz = wv.z - xv.z, dw = wv.w - xv.w;
        lsum = fmaf(dx, dx, lsum); lsum = fmaf(dy, dy, lsum);
        lsum = fmaf(dz, dz, lsum); lsum = fmaf(dw, dw, lsum);
    }
    #pragma unroll
    for (int off = 32; off > 0; off >>= 1)
        lsum += __shfl_down(lsum, off, 64);
    if ((tid & 63) == 0) atomicAdd(loss_accum, lsum);
}

__global__ void vq_finalize(const float* __restrict__ ws, float* __restrict__ loss_out) {
    // loss = q_latent + 0.25*e_latent = 1.25 * mean((quant - x)^2)
    loss_out[0] = 1.25f * ws[0] / (float)ND_TOTAL;
}

extern "C" void kernel_launch(void* const* d_in, const int* in_sizes, int n_in,
                              void* d_out, int out_size, void* d_ws, size_t ws_size,
                              hipStream_t stream) {
    const float* x = (const float*)d_in[0];
    const float* W = (const float*)d_in[1];
    float* out = (float*)d_out;
    float* ws  = (float*)d_ws;

    vq_prep<<<4, 256, 0, stream>>>(W, ws);
    vq_main<<<NROWS / BM, 256, 0, stream>>>(x, W, ws + 64, out, ws,
                                            out + (size_t)ND_TOTAL + 1);
    vq_finalize<<<1, 1, 0, stream>>>(ws, out + ND_TOTAL);
}

// Round 9
// 399.818 us; speedup vs baseline: 1.3213x; 1.3213x over previous
//
#include <hip/hip_runtime.h>

// VectorQuantizer via bf16 hi/lo MFMA GEMM, TWO passes (normal + swapped-half B)
// giving S = (x_hi+x_lo)·(w_hi+w_lo) exactly in f32 accumulation.
// Candidate top-2 per code-half + exact f32 rescore (proven machinery from R7 run).
// x[65536,256] f32, W[1024,256] f32.
// Out (f32, concat): quantized[16777216] | loss[1] | idx[65536].
// Xhat (bf16 [hi|lo] per row, 64 MB) lives in d_out until each block overwrites
// its own rows with quantized in the epilogue (disjoint row ranges per block).

#define NROWS    65536
#define DDIM     256
#define KCODES   1024
#define DEXT     512        // [hi(256) | lo(256)] bf16
#define ND_TOTAL 16777216

typedef __attribute__((ext_vector_type(8))) short bf16x8;
typedef __attribute__((ext_vector_type(4))) float floatx4;

__device__ __forceinline__ unsigned short f2bf(float f) {
    unsigned int u = __float_as_uint(f);
    return (unsigned short)((u + 0x7FFFu + ((u >> 16) & 1u)) >> 16);
}
__device__ __forceinline__ float bf2f(unsigned short h) {
    return __uint_as_float((unsigned int)h << 16);
}
__device__ __forceinline__ void split4(float4 v, ushort4* hi, ushort4* lo) {
    unsigned short hx = f2bf(v.x), hy = f2bf(v.y), hz = f2bf(v.z), hw = f2bf(v.w);
    *hi = make_ushort4(hx, hy, hz, hw);
    *lo = make_ushort4(f2bf(v.x - bf2f(hx)), f2bf(v.y - bf2f(hy)),
                       f2bf(v.z - bf2f(hz)), f2bf(v.w - bf2f(hw)));
}
__device__ __forceinline__ void async_copy16(void* lds, const void* g) {
    __builtin_amdgcn_global_load_lds(
        (const __attribute__((address_space(1))) unsigned int*)g,
        (__attribute__((address_space(3))) unsigned int*)lds, 16, 0, 0);
}

// merge top-2 (v1,k1,v2,k2) with (o1,ok1,o2,ok2); lowest-k on ties
__device__ __forceinline__ void merge2(float& v1, int& k1, float& v2, int& k2,
                                       float o1, int ok1, float o2, int ok2) {
    bool aw = (v1 < o1) || (v1 == o1 && k1 < ok1);
    float ca = aw ? v2 : v1; int kca = aw ? k2 : k1;
    float cb = aw ? o1 : o2; int kcb = aw ? ok1 : ok2;
    float nv1 = aw ? v1 : o1; int nk1 = aw ? k1 : ok1;
    bool cw = (ca < cb) || (ca == cb && kca < kcb);
    v1 = nv1; k1 = nk1;
    v2 = cw ? ca : cb; k2 = cw ? kca : kcb;
}

// ws: What[1024*512 ushort] (1MB) | w2[1024] | w2m[1024] | loss[1]
__global__ void vq_prepw(const float* __restrict__ W, unsigned short* __restrict__ What,
                         float* __restrict__ w2, float* __restrict__ w2m,
                         float* __restrict__ lossws) {
    int k = blockIdx.x * 256 + threadIdx.x;
    if (k == 0) lossws[0] = 0.0f;
    if (k >= KCODES) return;
    const float4* wr = (const float4*)(W + (size_t)k * DDIM);
    unsigned short* hrow = What + (size_t)k * DEXT;
    float s = 0.0f;
    for (int i = 0; i < 64; ++i) {
        float4 v = wr[i];
        s = fmaf(v.x, v.x, s); s = fmaf(v.y, v.y, s);
        s = fmaf(v.z, v.z, s); s = fmaf(v.w, v.w, s);
        ushort4 hv, lv;
        split4(v, &hv, &lv);
        *(ushort4*)(hrow + i * 4) = hv;
        *(ushort4*)(hrow + 256 + i * 4) = lv;
    }
    w2[k] = s;
    w2m[k] = s - 256.0f;
}

__global__ void vq_convx(const float* __restrict__ x, unsigned short* Xhat) {
    int gid = blockIdx.x * 256 + threadIdx.x;
    int row = gid >> 6, q = gid & 63;
    float4 v = ((const float4*)x)[gid];
    ushort4 hv, lv;
    split4(v, &hv, &lv);
    unsigned short* r = Xhat + (size_t)row * DEXT;
    *(ushort4*)(r + q * 4) = hv;
    *(ushort4*)(r + 256 + q * 4) = lv;
}

__global__ __launch_bounds__(256, 2) void vq_main(
    const unsigned short* Xhat, const unsigned short* __restrict__ What,
    const float* __restrict__ x, const float* __restrict__ W,
    const float* __restrict__ w2, const float* __restrict__ w2m,
    float* qout, float* lossws, float* idx_out)
{
    __shared__ unsigned short As[128 * 32];   // 8 KB  [row][32]
    __shared__ unsigned short Bs[128 * 32];   // 8 KB  [code][32]
    __shared__ float Wm[KCODES];              // 4 KB staged w2m
    __shared__ float rv1[2][128], rv2[2][128];
    __shared__ int   rk1[2][128], rk2[2][128];
    __shared__ int   candk[128][4];
    __shared__ float resc[128][4];
    __shared__ int   fink[128];

    const int tid  = threadIdx.x;
    const int wave = tid >> 6, lane = tid & 63;
    const int quad = lane >> 4, l15 = lane & 15;
    const int wr = wave >> 1, wc = wave & 1;
    const int row0 = blockIdx.x * 128;

    // stage w2m (first use is after the first __syncthreads inside the loop)
    #pragma unroll
    for (int t = 0; t < 4; ++t) Wm[t * 256 + tid] = w2m[t * 256 + tid];

    // in-lane packed top-2: low 5 mantissa bits = payload (j<<3)|ct, err <= 31 ulp
    float s1[16], s2[16];
    #pragma unroll
    for (int s = 0; s < 16; ++s) { s1[s] = 3.0e38f; s2[s] = 3.0e38f; }

    const int g0 = wave * 64 + lane, g1 = 256 + g0;   // LDS = wave-uniform + lane*16B
    const int r0 = g0 >> 2, p0 = g0 & 3;
    const int r1 = g1 >> 2, p1 = g1 & 3;
    const unsigned short* Ab = Xhat + (size_t)row0 * DEXT;

    #pragma unroll 1
    for (int ct = 0; ct < 8; ++ct) {
        floatx4 acc[4][4];
        #pragma unroll
        for (int i = 0; i < 4; ++i)
            #pragma unroll
            for (int j = 0; j < 4; ++j) acc[i][j] = (floatx4){0.f, 0.f, 0.f, 0.f};

        const unsigned short* Bb = What + (size_t)(ct * 128) * DEXT;

        // pass 0: B at dc        -> ah*bh + al*bl
        // pass 1: B at dc^256    -> ah*bl + al*bh
        // sum = (ah+al)*(bh+bl) exactly (f32 accumulation)
        #pragma unroll 1
        for (int p = 0; p < 2; ++p) {
            const int bswap = p << 8;   // 0 or 256; dc chunks never straddle halves
            #pragma unroll 1
            for (int dc = 0; dc < DEXT; dc += 32) {
                const int bdc = dc ^ bswap;
                __syncthreads();
                async_copy16(As + g0 * 8, Ab + (size_t)r0 * DEXT + dc + p0 * 8);
                async_copy16(As + g1 * 8, Ab + (size_t)r1 * DEXT + dc + p1 * 8);
                async_copy16(Bs + g0 * 8, Bb + (size_t)r0 * DEXT + bdc + p0 * 8);
                async_copy16(Bs + g1 * 8, Bb + (size_t)r1 * DEXT + bdc + p1 * 8);
                __syncthreads();
                bf16x8 a[4], b[4];
                #pragma unroll
                for (int i = 0; i < 4; ++i)
                    a[i] = *(const bf16x8*)(As + ((wr * 64 + i * 16 + l15) * 32 + quad * 8));
                #pragma unroll
                for (int j = 0; j < 4; ++j)
                    b[j] = *(const bf16x8*)(Bs + ((wc * 64 + j * 16 + l15) * 32 + quad * 8));
                #pragma unroll
                for (int i = 0; i < 4; ++i)
                    #pragma unroll
                    for (int j = 0; j < 4; ++j)
                        acc[i][j] = __builtin_amdgcn_mfma_f32_16x16x32_bf16(a[i], b[j], acc[i][j], 0, 0, 0);
            }
        }

        // fold: v = (w2-256) - 2*S, payload = (j<<3)|ct in low 5 bits
        #pragma unroll
        for (int j = 0; j < 4; ++j) {
            int c = ct * 128 + wc * 64 + j * 16 + l15;
            float wm = Wm[c];
            unsigned pay = (unsigned)((j << 3) | ct);
            #pragma unroll
            for (int i = 0; i < 4; ++i)
                #pragma unroll
                for (int r = 0; r < 4; ++r) {
                    float v = fmaf(-2.0f, acc[i][j][r], wm);
                    float pf = __uint_as_float((__float_as_uint(v) & 0xFFFFFFE0u) | pay);
                    int s = i * 4 + r;
                    float t = fminf(s1[s], pf);
                    s2[s] = fminf(s2[s], fmaxf(s1[s], pf));
                    s1[s] = t;
                }
        }
    }

    // decode packed top-2 -> explicit (val, code)
    float v1[16], v2[16];
    int k1[16], k2[16];
    #pragma unroll
    for (int s = 0; s < 16; ++s) {
        unsigned u1 = __float_as_uint(s1[s]) & 31u;
        unsigned u2 = __float_as_uint(s2[s]) & 31u;
        v1[s] = s1[s]; v2[s] = s2[s];
        k1[s] = (int)(u1 & 7u) * 128 + wc * 64 + (int)(u1 >> 3) * 16 + l15;
        k2[s] = (int)(u2 & 7u) * 128 + wc * 64 + (int)(u2 >> 3) * 16 + l15;
    }
    // cross-lane merge across the 16 l15 lanes (explicit val+idx)
    #pragma unroll
    for (int m = 1; m < 16; m <<= 1) {
        #pragma unroll
        for (int s = 0; s < 16; ++s) {
            float o1 = __shfl_xor(v1[s], m, 64);
            int  ok1 = __shfl_xor(k1[s], m, 64);
            float o2 = __shfl_xor(v2[s], m, 64);
            int  ok2 = __shfl_xor(k2[s], m, 64);
            merge2(v1[s], k1[s], v2[s], k2[s], o1, ok1, o2, ok2);
        }
    }
    if (l15 == 0) {   // publish per-half top-2 for all 16 row-slots
        #pragma unroll
        for (int s = 0; s < 16; ++s) {
            int row = wr * 64 + (s >> 2) * 16 + quad * 4 + (s & 3);
            rv1[wc][row] = v1[s]; rk1[wc][row] = k1[s];
            rv2[wc][row] = v2[s]; rk2[wc][row] = k2[s];
        }
    }
    __syncthreads();
    if (tid < 128) {   // 4 candidates per row: top-2 from each disjoint code-half
        candk[tid][0] = rk1[0][tid];
        candk[tid][1] = rk2[0][tid];
        candk[tid][2] = rk1[1][tid];
        candk[tid][3] = rk2[1][tid];
    }
    __syncthreads();
    // exact f32 rescore of all 4 candidates (512 jobs, 2 per thread)
    #pragma unroll
    for (int j2 = 0; j2 < 2; ++j2) {
        int job = tid + j2 * 256;
        int r = job >> 2, cn = job & 3;
        int k = candk[r][cn];
        const float4* xr  = (const float4*)(x + (size_t)(row0 + r) * DDIM);
        const float4* wrp = (const float4*)(W + (size_t)k * DDIM);
        float dot = 0.0f;
        #pragma unroll 8
        for (int i = 0; i < 64; ++i) {
            float4 va = xr[i], vb = wrp[i];
            dot = fmaf(va.x, vb.x, dot); dot = fmaf(va.y, vb.y, dot);
            dot = fmaf(va.z, vb.z, dot); dot = fmaf(va.w, vb.w, dot);
        }
        resc[r][cn] = fmaf(-2.0f, dot, w2[k]);
    }
    __syncthreads();
    if (tid < 128) {
        float bd = resc[tid][0];
        int   bk = candk[tid][0];
        #pragma unroll
        for (int cn = 1; cn < 4; ++cn) {
            float d = resc[tid][cn];
            int   k = candk[tid][cn];
            if (d < bd || (d == bd && k < bk)) { bd = d; bk = k; }
        }
        fink[tid] = bk;
        idx_out[row0 + tid] = (float)bk;
    }
    __syncthreads();

    // epilogue: gather W[idx] -> quantized (overwrites this block's Xhat rows), loss
    const int c4 = tid & 63, rsub = tid >> 6;
    float lsum = 0.0f;
    for (int it2 = 0; it2 < 32; ++it2) {
        int r = it2 * 4 + rsub;
        int k = fink[r];
        float4 wv = ((const float4*)(W + (size_t)k * DDIM))[c4];
        float4 xv = ((const float4*)(x + (size_t)(row0 + r) * DDIM))[c4];
        ((float4*)(qout + (size_t)(row0 + r) * DDIM))[c4] = wv;
        float dx = wv.x - xv.x, dy = wv.y - xv.y;
        float dz = wv.z - xv.z, dw = wv.w - xv.w;
        lsum = fmaf(dx, dx, lsum); lsum = fmaf(dy, dy, lsum);
        lsum = fmaf(dz, dz, lsum); lsum = fmaf(dw, dw, lsum);
    }
    #pragma unroll
    for (int off = 32; off > 0; off >>= 1) lsum += __shfl_down(lsum, off, 64);
    if (lane == 0) atomicAdd(lossws, lsum);
}

__global__ void vq_fin(const float* __restrict__ lossws, float* __restrict__ loss_out) {
    loss_out[0] = 1.25f * lossws[0] / (float)ND_TOTAL;
}

extern "C" void kernel_launch(void* const* d_in, const int* in_sizes, int n_in,
                              void* d_out, int out_size, void* d_ws, size_t ws_size,
                              hipStream_t stream) {
    const float* x = (const float*)d_in[0];
    const float* W = (const float*)d_in[1];
    float* out = (float*)d_out;
    unsigned short* Xhat = (unsigned short*)d_out;
    unsigned short* What = (unsigned short*)d_ws;
    float* w2     = (float*)((char*)d_ws + (1 << 20));
    float* w2m    = w2 + 1024;
    float* lossws = w2 + 2048;
    float* idx_out = out + (size_t)ND_TOTAL + 1;

    vq_prepw<<<4, 256, 0, stream>>>(W, What, w2, w2m, lossws);
    vq_convx<<<16384, 256, 0, stream>>>(x, Xhat);
    vq_main<<<512, 256, 0, stream>>>(Xhat, What, x, W, w2, w2m, out, lossws, idx_out);
    vq_fin<<<1, 1, 0, stream>>>(lossws, out + ND_TOTAL);
}